// Round 5
// baseline (315.800 us; speedup 1.0000x reference)
//
#include <hip/hip_runtime.h>
#include <stdint.h>
#include <stddef.h>

// Problem constants (fixed by setup_inputs)
#define N_ROWS 500000
#define DDIM   128
#define K2     256      // 2*D
#define KBOND  32
#define TILE2  32
#define NT2    (N_ROWS / TILE2)   // 15625, exact (no tail!)
#define NB     512                // persistent pass1 blocks (2/CU target)
#define P2_BLOCKS 2048

typedef float  f32x4  __attribute__((ext_vector_type(4)));
typedef __bf16 bf16x8 __attribute__((ext_vector_type(8)));
typedef __bf16 bf16x4 __attribute__((ext_vector_type(4)));

// ---- module-scope device scratch ----
__device__ __bf16 g_wbf[DDIM * K2];                    // 64 KiB  W_i_w bf16 [d][k]
__device__ float  g_s[N_ROWS];                         // 2 MiB   s[n] = colsum(bond)
__device__ float  g_partials[NB * DDIM];               // 256 KiB
__device__ float  g_msg[DDIM];
__device__ __bf16 g_hn[(size_t)N_ROWS * DDIM];         // 128 MiB h_n bf16

// ---- kernel 1: W_i_w f32 -> bf16 ----
__global__ void k_prep(const float* __restrict__ w) {
  int t = blockIdx.x * blockDim.x + threadIdx.x;
  if (t < DDIM * K2) g_wbf[t] = (__bf16)w[t];
}

// ---- kernel 1b: s[n] = sum_k bond[k][n]  (pure streaming, ~64 MB) ----
__global__ __launch_bounds__(256)
void k_s(const float* __restrict__ bond) {
  int n = blockIdx.x * 256 + threadIdx.x;
  if (n >= N_ROWS) return;
  float a = 0.f, b = 0.f;
  #pragma unroll
  for (int k = 0; k < KBOND; k += 2) {          // 2 chains, 32 independent loads
    a += bond[(size_t)k * N_ROWS + n];
    b += bond[(size_t)(k + 1) * N_ROWS + n];
  }
  g_s[n] = a + b;
}

// async global->LDS, 16 B per lane (m97 pattern)
static __device__ __forceinline__ void gload16(const float* g, float* l) {
  __builtin_amdgcn_global_load_lds(
      (const __attribute__((address_space(1))) void*)g,
      (__attribute__((address_space(3))) void*)l, 16, 0, 0);
}

// ---- kernel 2: fused h_n GEMM + m partial accumulation ----
// Persistent: 512 blocks x 512 threads (8 waves), 32-row tiles, grid-stride
// by NB. Double-buffered f32 A-tile in LDS (2 x 32 KiB), staged via
// global_load_lds (no staging registers), ONE barrier per tile.
// Wave w owns d in [16w,16w+16) with W fragments resident in registers.
// MFMA swapped (A=W rows=d, B=data cols=n): lane -> n = l15 (+16 for acc1),
// d = 16w + 4g + reg. A/B use the identical (g,e)->k map so any internal
// k-permutation cancels (verified rounds 2-4).
// LDS layout: row r (0..31) at r*1024 B; within-row byte = k4B ^ ((r&7)<<4).
// Staged with linear LDS dest + pre-swizzled GLOBAL source (G21):
//   issue j, wave w stages row w+8j; lane's source col = 4*((lane&31)^w),
//   lanes 0-31 cover the x half, lanes 32-63 the h_e half.
__global__ __launch_bounds__(512, 4)
void k_pass1(const float* __restrict__ x, const float* __restrict__ he,
             const float* __restrict__ bias)
{
  __shared__ float a_lds[2][TILE2 * K2];   // 2 x 32 KiB = 64 KiB exactly

  const int tid  = threadIdx.x;
  const int w    = tid >> 6;        // wave 0..7
  const int lane = tid & 63;
  const int l15  = lane & 15;
  const int g    = lane >> 4;       // 0..3

  // W fragments, all K, in registers (loaded once per block): 32 VGPR
  bf16x8 wfrag[8];
  #pragma unroll
  for (int ks = 0; ks < 8; ++ks)
    wfrag[ks] = *(const bf16x8*)(g_wbf + (size_t)(16 * w + l15) * K2 + 32 * ks + 8 * g);

  const int d0 = 16 * w + 4 * g;
  const f32x4 bv = *(const f32x4*)(bias + d0);

  // per-lane staging source base (swizzle pre-applied to global col)
  const float* sbase = ((lane < 32) ? x : he) + 4 * ((lane & 31) ^ w);

  f32x4 macc = (f32x4)(0.f);

  // ---- prologue: stage tile t0 into buf0 ----
  int t = blockIdx.x;
  {
    const size_t rowb = (size_t)(t * TILE2 + w) * DDIM;
    #pragma unroll
    for (int j = 0; j < 4; ++j)
      gload16(sbase + rowb + (size_t)(8 * j) * DDIM,
              &a_lds[0][(512 * j + 64 * w) * 4]);
  }
  float s0 = g_s[t * TILE2 + l15];
  float s1 = g_s[t * TILE2 + 16 + l15];
  __syncthreads();

  int cur = 0;
  while (true) {
    const int  tn  = t + NB;
    const bool has = tn < NT2;
    float s0n = 0.f, s1n = 0.f;

    // issue next tile's staging (lands in buf^1 during our compute)
    if (has) {
      const size_t rowb = (size_t)(tn * TILE2 + w) * DDIM;
      #pragma unroll
      for (int j = 0; j < 4; ++j)
        gload16(sbase + rowb + (size_t)(8 * j) * DDIM,
                &a_lds[cur ^ 1][(512 * j + 64 * w) * 4]);
      s0n = g_s[tn * TILE2 + l15];
      s1n = g_s[tn * TILE2 + 16 + l15];
    }

    // ---- compute from buf[cur]: cvt-on-read + MFMA ----
    f32x4 acc0 = (f32x4)(0.f), acc1 = (f32x4)(0.f);
    const char* base = (const char*)&a_lds[cur][0];
    const int sw = (l15 & 7) << 4;
    #pragma unroll
    for (int ks = 0; ks < 8; ++ks) {
      const int o = 128 * ks + 32 * g;
      f32x4 u0 = *(const f32x4*)(base + l15 * 1024        + ((o)      ^ sw));
      f32x4 u1 = *(const f32x4*)(base + l15 * 1024        + ((o + 16) ^ sw));
      f32x4 v0 = *(const f32x4*)(base + (16 + l15) * 1024 + ((o)      ^ sw));
      f32x4 v1 = *(const f32x4*)(base + (16 + l15) * 1024 + ((o + 16) ^ sw));
      bf16x8 b0, b1;
      #pragma unroll
      for (int i = 0; i < 4; ++i) {
        b0[i] = (__bf16)u0[i]; b0[4 + i] = (__bf16)u1[i];
        b1[i] = (__bf16)v0[i]; b1[4 + i] = (__bf16)v1[i];
      }
      acc0 = __builtin_amdgcn_mfma_f32_16x16x32_bf16(wfrag[ks], b0, acc0, 0, 0, 0);
      acc1 = __builtin_amdgcn_mfma_f32_16x16x32_bf16(wfrag[ks], b1, acc1, 0, 0, 0);
    }

    __syncthreads();   // drains stage(tn) loads; buf[cur] reads complete

    // ---- epilogue AFTER barrier: stores drain at NEXT barrier (hidden) ----
    {
      const int rb = t * TILE2;
      f32x4 h0, h1;
      #pragma unroll
      for (int i = 0; i < 4; ++i) {
        float a = acc0[i] + bv[i]; h0[i] = a > 0.f ? a : 0.f;
        float b = acc1[i] + bv[i]; h1[i] = b > 0.f ? b : 0.f;
      }
      macc += s0 * h0 + s1 * h1;
      bf16x4 hb0, hb1;
      #pragma unroll
      for (int i = 0; i < 4; ++i) { hb0[i] = (__bf16)h0[i]; hb1[i] = (__bf16)h1[i]; }
      *(bf16x4*)(g_hn + (size_t)(rb + l15) * DDIM + d0)      = hb0;
      *(bf16x4*)(g_hn + (size_t)(rb + 16 + l15) * DDIM + d0) = hb1;
    }

    if (!has) break;
    cur ^= 1; t = tn; s0 = s0n; s1 = s1n;
  }

  // ---- block partial for m: sum the 16 l15-lanes (same d0 quad) ----
  #pragma unroll
  for (int off = 1; off <= 8; off <<= 1) {
    #pragma unroll
    for (int i = 0; i < 4; ++i) macc[i] += __shfl_xor(macc[i], off, 64);
  }
  if (l15 == 0)
    *(f32x4*)(&g_partials[(size_t)blockIdx.x * DDIM + d0]) = macc;
}

// ---- kernel 4: m[d] = sum_c partials[c][d]; msg = W_m m + b_m ----
__global__ void k_msg(const float* __restrict__ wm, const float* __restrict__ bm) {
  __shared__ float ms[DDIM];
  __shared__ float sp[DDIM];
  const int d    = threadIdx.x & 127;     // 256 threads
  const int half = threadIdx.x >> 7;
  float s = 0.f;
  for (int c = half; c < NB; c += 2) s += g_partials[c * DDIM + d];
  if (half == 0) sp[d] = s;
  __syncthreads();
  if (half == 1) ms[d] = sp[d] + s;
  __syncthreads();
  if (half == 0) {
    float acc = bm[d];
    #pragma unroll 8
    for (int j = 0; j < DDIM; ++j) acc += ms[j] * wm[(size_t)d * DDIM + j];
    g_msg[d] = acc;
  }
}

// ---- kernel 5: out = relu(h_n + msg) ----
__global__ __launch_bounds__(256)
void k_pass2(float* __restrict__ out)
{
  __shared__ float ms[DDIM];
  if (threadIdx.x < DDIM) ms[threadIdx.x] = g_msg[threadIdx.x];
  __syncthreads();
  const size_t total = (size_t)N_ROWS * DDIM / 8;
  for (size_t c = (size_t)blockIdx.x * blockDim.x + threadIdx.x; c < total;
       c += (size_t)gridDim.x * blockDim.x) {
    const size_t base = c * 8;
    const int col0 = (int)(base & (DDIM - 1));
    bf16x8 hv = *(const bf16x8*)(g_hn + base);
    f32x4 o0, o1;
    #pragma unroll
    for (int i = 0; i < 4; ++i) {
      float a = (float)hv[i]     + ms[col0 + i];
      float b = (float)hv[4 + i] + ms[col0 + 4 + i];
      o0[i] = a > 0.f ? a : 0.f;
      o1[i] = b > 0.f ? b : 0.f;
    }
    *(f32x4*)(out + base)     = o0;
    *(f32x4*)(out + base + 4) = o1;
  }
}

extern "C" void kernel_launch(void* const* d_in, const int* in_sizes, int n_in,
                              void* d_out, int out_size, void* d_ws, size_t ws_size,
                              hipStream_t stream) {
  const float* x    = (const float*)d_in[0];
  const float* he   = (const float*)d_in[1];
  const float* bond = (const float*)d_in[2];
  const float* wi   = (const float*)d_in[3];
  const float* bi   = (const float*)d_in[4];
  const float* wm   = (const float*)d_in[5];
  const float* bm   = (const float*)d_in[6];
  float* out = (float*)d_out;
  (void)d_ws; (void)ws_size;

  k_prep<<<(DDIM * K2 + 255) / 256, 256, 0, stream>>>(wi);
  k_s<<<(N_ROWS + 255) / 256, 256, 0, stream>>>(bond);
  k_pass1<<<NB, 512, 0, stream>>>(x, he, bi);
  k_msg<<<1, 256, 0, stream>>>(wm, bm);
  k_pass2<<<P2_BLOCKS, 256, 0, stream>>>(out);
}

// Round 6
// 266.489 us; speedup vs baseline: 1.1850x; 1.1850x over previous
//
#include <hip/hip_runtime.h>
#include <stdint.h>
#include <stddef.h>

// Problem constants (fixed by setup_inputs)
#define N_ROWS 500000
#define DDIM   128
#define K2     256      // 2*D
#define KBOND  32
#define TILE   32
#define NTL    (N_ROWS / TILE)    // 15625, exact
#define NBLK   1536               // persistent pass1 blocks (~3/CU wave-slots)
#define MR_BLKS 24                // 1536 / 64
#define P2_BLOCKS 2048

typedef float  f32x4  __attribute__((ext_vector_type(4)));
typedef __bf16 bf16x8 __attribute__((ext_vector_type(8)));
typedef __bf16 bf16x4 __attribute__((ext_vector_type(4)));

// ---- module-scope device scratch ----
__device__ __bf16 g_wbf[DDIM * K2];                    // 64 KiB  W_i_w bf16 [d][k]
__device__ float  g_s[N_ROWS];                         // 2 MiB   s[n] = colsum(bond)
__device__ float  g_partials[NBLK * DDIM];             // 768 KiB
__device__ float  g_p2[MR_BLKS * DDIM];                // 12 KiB
__device__ float  g_msg[DDIM];
__device__ __bf16 g_hn[(size_t)N_ROWS * DDIM];         // 128 MiB h_n bf16

// ---- kernel 1: W_i_w f32 -> bf16 ----
__global__ void k_prep(const float* __restrict__ w) {
  int t = blockIdx.x * blockDim.x + threadIdx.x;
  if (t < DDIM * K2) g_wbf[t] = (__bf16)w[t];
}

// ---- kernel 1b: s[n] = sum_k bond[k][n]  (pure streaming, ~64 MB) ----
__global__ __launch_bounds__(256)
void k_s(const float* __restrict__ bond) {
  int n = blockIdx.x * 256 + threadIdx.x;
  if (n >= N_ROWS) return;
  float a = 0.f, b = 0.f;
  #pragma unroll
  for (int k = 0; k < KBOND; k += 2) {
    a += bond[(size_t)k * N_ROWS + n];
    b += bond[(size_t)(k + 1) * N_ROWS + n];
  }
  g_s[n] = a + b;
}

// ---- kernel 2: fused h_n GEMM + m partial accumulation ----
// Persistent: NBLK blocks x 512 threads (8 waves), 32-row tiles, stride NBLK.
// T14 async-STAGE split: issue global loads for tile t+1 (registers) at loop
// top; compute tile t from bf16 LDS; AFTER epilogue, cvt+ds_write the staged
// regs into buf^1; ONE __syncthreads per tile (its vmcnt(0) drain only covers
// cheap L2-bound h_n stores -- the HBM loads were consumed before it).
// sched_barrier(0) pins the load-issue above the compute phase; the loop body
// is a single BB (clamped last-iter load) so nothing can be sunk.
// LDS: R4's measured-zero-conflict bf16 layout. Row r (0..31) at r*512 B,
// byte(r, slot) = r*512 + (16*slot ^ ((r&15)<<4)); x = slots 0-15 (k 0..127),
// he at +256 B (k 128..255). Read fragment (ks,g) = phys slot (4ks+g)^(r&15).
// MFMA swapped (A=W rows=d, B=data cols=n); A/B share the (g,e)->k map
// k = 32ks+8g+e, so any internal k-permutation cancels (verified R2-R5).
__global__ __launch_bounds__(512)
void k_pass1(const float* __restrict__ x, const float* __restrict__ he,
             const float* __restrict__ bias)
{
  __shared__ __align__(16) unsigned char a_lds[2][TILE * 512];   // 2 x 16 KiB

  const int tid  = threadIdx.x;
  const int w    = tid >> 6;        // wave 0..7: owns d in [16w, 16w+16)
  const int lane = tid & 63;
  const int l15  = lane & 15;
  const int g    = lane >> 4;       // 0..3

  // W fragments, all K, in registers (loaded once): 32 VGPR
  bf16x8 wfrag[8];
  #pragma unroll
  for (int ks = 0; ks < 8; ++ks)
    wfrag[ks] = *(const bf16x8*)(g_wbf + (size_t)(16 * w + l15) * K2 + 32 * ks + 8 * g);

  const int d0 = 16 * w + 4 * g;
  const f32x4 bv = *(const f32x4*)(bias + d0);

  // staging coordinates: thread -> (row sr, 16B slot sc)
  const int sr = tid >> 4;                       // 0..31
  const int sc = tid & 15;                       // 0..15
  const unsigned swz   = (unsigned)((sr & 15) << 4);
  const unsigned wo_x  = (unsigned)(sr * 512) + ((16u * sc) ^ swz);
  const unsigned wo_he = (unsigned)(sr * 512) + 256u + ((16u * sc) ^ swz);
  const unsigned rsw   = (unsigned)(l15 << 4);   // read-side swizzle (r&15 == l15)

  f32x4 macc = (f32x4)(0.f);

  int t = blockIdx.x;

  // ---- prologue: stage tile t into buf 0 ----
  {
    const float* xr = x  + (size_t)(t * TILE + sr) * DDIM + 8 * sc;
    const float* hr = he + (size_t)(t * TILE + sr) * DDIM + 8 * sc;
    f32x4 xa = *(const f32x4*)xr, xb = *(const f32x4*)(xr + 4);
    f32x4 ha = *(const f32x4*)hr, hb = *(const f32x4*)(hr + 4);
    bf16x8 bx, bh;
    #pragma unroll
    for (int i = 0; i < 4; ++i) {
      bx[i] = (__bf16)xa[i]; bx[4 + i] = (__bf16)xb[i];
      bh[i] = (__bf16)ha[i]; bh[4 + i] = (__bf16)hb[i];
    }
    *(bf16x8*)(&a_lds[0][wo_x])  = bx;
    *(bf16x8*)(&a_lds[0][wo_he]) = bh;
  }
  float s0 = g_s[t * TILE + l15];
  float s1 = g_s[t * TILE + 16 + l15];
  __syncthreads();

  int cur = 0;
  while (true) {
    const int  tn  = t + NBLK;
    const bool has = tn < NTL;
    const int  tl  = has ? tn : t;              // clamp: keep body single-BB

    // ---- early-issue next tile's global loads (held in registers) ----
    const float* xr = x  + (size_t)(tl * TILE + sr) * DDIM + 8 * sc;
    const float* hr = he + (size_t)(tl * TILE + sr) * DDIM + 8 * sc;
    f32x4 xa = *(const f32x4*)xr, xb = *(const f32x4*)(xr + 4);
    f32x4 ha = *(const f32x4*)hr, hb = *(const f32x4*)(hr + 4);
    float s0n = g_s[tl * TILE + l15];
    float s1n = g_s[tl * TILE + 16 + l15];
    __builtin_amdgcn_sched_barrier(0);

    // ---- compute tile t from buf[cur] ----
    f32x4 acc0 = (f32x4)(0.f), acc1 = (f32x4)(0.f);
    const unsigned char* base = &a_lds[cur][0];
    #pragma unroll
    for (int ks = 0; ks < 8; ++ks) {
      const unsigned o = (unsigned)(64 * ks + 16 * g);
      bf16x8 b0 = *(const bf16x8*)(base + l15 * 512        + (o ^ rsw));
      bf16x8 b1 = *(const bf16x8*)(base + (16 + l15) * 512 + (o ^ rsw));
      acc0 = __builtin_amdgcn_mfma_f32_16x16x32_bf16(wfrag[ks], b0, acc0, 0, 0, 0);
      acc1 = __builtin_amdgcn_mfma_f32_16x16x32_bf16(wfrag[ks], b1, acc1, 0, 0, 0);
    }

    // ---- epilogue tile t: bias+relu, m partial, h_n stores (L2-bound) ----
    {
      const int rb = t * TILE;
      f32x4 h0, h1;
      #pragma unroll
      for (int i = 0; i < 4; ++i) {
        float a = acc0[i] + bv[i]; h0[i] = a > 0.f ? a : 0.f;
        float b = acc1[i] + bv[i]; h1[i] = b > 0.f ? b : 0.f;
      }
      #pragma unroll
      for (int i = 0; i < 4; ++i) macc[i] += s0 * h0[i] + s1 * h1[i];
      bf16x4 hb0, hb1;
      #pragma unroll
      for (int i = 0; i < 4; ++i) { hb0[i] = (__bf16)h0[i]; hb1[i] = (__bf16)h1[i]; }
      *(bf16x4*)(g_hn + (size_t)(rb + l15) * DDIM + d0)      = hb0;
      *(bf16x4*)(g_hn + (size_t)(rb + 16 + l15) * DDIM + d0) = hb1;
    }
    __builtin_amdgcn_sched_barrier(0);

    // ---- write staged regs into buf[cur^1] (compiler waits its own loads) ----
    {
      bf16x8 bx, bh;
      #pragma unroll
      for (int i = 0; i < 4; ++i) {
        bx[i] = (__bf16)xa[i]; bx[4 + i] = (__bf16)xb[i];
        bh[i] = (__bf16)ha[i]; bh[4 + i] = (__bf16)hb[i];
      }
      *(bf16x8*)(&a_lds[cur ^ 1][wo_x])  = bx;
      *(bf16x8*)(&a_lds[cur ^ 1][wo_he]) = bh;
    }
    __syncthreads();

    if (!has) break;
    t = tn; cur ^= 1; s0 = s0n; s1 = s1n;
  }

  // ---- block partial for m: sum the 16 l15-lanes (same d0 quad) ----
  #pragma unroll
  for (int off = 1; off <= 8; off <<= 1) {
    #pragma unroll
    for (int i = 0; i < 4; ++i) macc[i] += __shfl_xor(macc[i], off, 64);
  }
  if (l15 == 0)
    *(f32x4*)(&g_partials[(size_t)blockIdx.x * DDIM + d0]) = macc;
}

// ---- kernel 3: parallel partial reduce: NBLK x 128 -> MR_BLKS x 128 ----
__global__ void k_mr() {
  const int d    = threadIdx.x & 127;
  const int half = threadIdx.x >> 7;        // 0/1
  const int r0   = blockIdx.x * 64;
  float acc = 0.f;
  for (int r = r0 + half; r < r0 + 64; r += 2)
    acc += g_partials[(size_t)r * DDIM + d];
  __shared__ float sp[DDIM];
  if (half == 0) sp[d] = acc;
  __syncthreads();
  if (half == 1) g_p2[blockIdx.x * DDIM + d] = sp[d] + acc;
}

// ---- kernel 4: m[d] = sum_c p2[c][d]; msg = W_m m + b_m ----
__global__ void k_msg(const float* __restrict__ wm, const float* __restrict__ bm) {
  __shared__ float ms[DDIM];
  const int d = threadIdx.x;                // 128 threads
  float s = 0.f;
  #pragma unroll
  for (int c = 0; c < MR_BLKS; ++c) s += g_p2[c * DDIM + d];
  ms[d] = s;
  __syncthreads();
  float acc = bm[d];
  #pragma unroll 8
  for (int j = 0; j < DDIM; ++j) acc += ms[j] * wm[(size_t)d * DDIM + j];
  g_msg[d] = acc;
}

// ---- kernel 5: out = relu(h_n + msg) ----
__global__ __launch_bounds__(256)
void k_pass2(float* __restrict__ out)
{
  __shared__ float ms[DDIM];
  if (threadIdx.x < DDIM) ms[threadIdx.x] = g_msg[threadIdx.x];
  __syncthreads();
  const size_t total = (size_t)N_ROWS * DDIM / 8;
  for (size_t c = (size_t)blockIdx.x * blockDim.x + threadIdx.x; c < total;
       c += (size_t)gridDim.x * blockDim.x) {
    const size_t base = c * 8;
    const int col0 = (int)(base & (DDIM - 1));
    bf16x8 hv = *(const bf16x8*)(g_hn + base);
    f32x4 o0, o1;
    #pragma unroll
    for (int i = 0; i < 4; ++i) {
      float a = (float)hv[i]     + ms[col0 + i];
      float b = (float)hv[4 + i] + ms[col0 + 4 + i];
      o0[i] = a > 0.f ? a : 0.f;
      o1[i] = b > 0.f ? b : 0.f;
    }
    *(f32x4*)(out + base)     = o0;
    *(f32x4*)(out + base + 4) = o1;
  }
}

extern "C" void kernel_launch(void* const* d_in, const int* in_sizes, int n_in,
                              void* d_out, int out_size, void* d_ws, size_t ws_size,
                              hipStream_t stream) {
  const float* x    = (const float*)d_in[0];
  const float* he   = (const float*)d_in[1];
  const float* bond = (const float*)d_in[2];
  const float* wi   = (const float*)d_in[3];
  const float* bi   = (const float*)d_in[4];
  const float* wm   = (const float*)d_in[5];
  const float* bm   = (const float*)d_in[6];
  float* out = (float*)d_out;
  (void)d_ws; (void)ws_size;

  k_prep<<<(DDIM * K2 + 255) / 256, 256, 0, stream>>>(wi);
  k_s<<<(N_ROWS + 255) / 256, 256, 0, stream>>>(bond);
  k_pass1<<<NBLK, 512, 0, stream>>>(x, he, bi);
  k_mr<<<MR_BLKS, 256, 0, stream>>>();
  k_msg<<<1, 128, 0, stream>>>(wm, bm);
  k_pass2<<<P2_BLOCKS, 256, 0, stream>>>(out);
}